// Round 18
// baseline (18005.252 us; speedup 1.0000x reference)
//
#include <hip/hip_runtime.h>
#include <cstdint>
#include <cstddef>

#define T_STEPS 1024
#define S_DIM   1024
#define A_DIM   64
#define D_DIM   2048
#define H_DIM   2048
#define NWG     256
#define NTHR    512    // 8 waves per WG, 1 WG per CU (forced by 140KB LDS)

typedef unsigned short ushort_t;
typedef unsigned long long u64;

__device__ __forceinline__ float eluf(float v)      { return v > 0.f ? v : expm1f(v); }
__device__ __forceinline__ float softplusf(float v) { return v > 20.f ? v : log1pf(expf(v)); }
__device__ __forceinline__ float sigmoidf_(float v) { return 1.f / (1.f + expf(-v)); }

__device__ __forceinline__ float wave_reduce(float v) {
  #pragma unroll
  for (int off = 32; off > 0; off >>= 1) v += __shfl_xor(v, off, 64);
  return v;
}

__device__ __forceinline__ float2 bf2(unsigned u) {
  float2 r;
  r.x = __uint_as_float(u << 16);
  r.y = __uint_as_float(u & 0xffff0000u);
  return r;
}
__device__ __forceinline__ ushort_t f2bf_rne(float f) {
  unsigned u = __float_as_uint(f);
  u += 0x7fffu + ((u >> 16) & 1u);
  return (ushort_t)(u >> 16);
}

// pinned (volatile) weight load: cannot be rematerialized/sunk into the loop.
#define LD_PIN_U4(dst, addr) \
  asm volatile("global_load_dwordx4 %0, %1, off" : "=v"(dst) : "v"(addr))

// ---- seqlock record {value lo32, generation hi32}, AGENT scope (MALL-coherent).
// Producer stores are fire-and-forget: NO drain needed (consumer verifies gens).
__device__ __forceinline__ void st_rec(u64* p, float v, unsigned g) {
  const u64 r = (u64)__float_as_uint(v) | ((u64)g << 32);
  __hip_atomic_store(p, r, __ATOMIC_RELAXED, __HIP_MEMORY_SCOPE_AGENT);
}
__device__ __forceinline__ u64 ld_rec(const u64* p) {
  return __hip_atomic_load(p, __ATOMIC_RELAXED, __HIP_MEMORY_SCOPE_AGENT);
}
__device__ __forceinline__ void st_flag(unsigned* p, unsigned g) {
  __hip_atomic_store(p, g, __ATOMIC_RELAXED, __HIP_MEMORY_SCOPE_AGENT);
}

// Wave-0 poll of 256 per-WG flags, each on its own 64B line (stride 16 u32).
// 4 batched dword loads per lane, one vmcnt per iteration; sc1 = agent scope.
// No RMW, no shared hot line (R13 lesson), tiny sweep (R15-proven).
__device__ __forceinline__ void poll_flags(const unsigned* f, unsigned g, int lane) {
  const unsigned* p0 = f + (lane * 4 + 0) * 16;
  const unsigned* p1 = f + (lane * 4 + 1) * 16;
  const unsigned* p2 = f + (lane * 4 + 2) * 16;
  const unsigned* p3 = f + (lane * 4 + 3) * 16;
  for (;;) {
    unsigned a, b, c, d;
    asm volatile("global_load_dword %0, %4, off sc1\n\t"
                 "global_load_dword %1, %5, off sc1\n\t"
                 "global_load_dword %2, %6, off sc1\n\t"
                 "global_load_dword %3, %7, off sc1\n\t"
                 "s_waitcnt vmcnt(0)"
                 : "=v"(a), "=v"(b), "=v"(c), "=v"(d)
                 : "v"(p0), "v"(p1), "v"(p2), "v"(p3) : "memory");
    if (__all(a >= g && b >= g && c >= g && d >= g)) return;
    __builtin_amdgcn_s_sleep(1);
  }
}

// Verify bulk-read of two uint4s (4 records), agent scope. After flag detection
// a retry is RARE (flag stored post-__syncthreads => all records issued first);
// gens make it safe. Deadlock-proof fallback after 4096 spins.
__device__ __forceinline__ void poll_pair(const u64* __restrict__ q0,
                                          const u64* __restrict__ q1,
                                          unsigned g, uint4& a, uint4& b) {
  int spins = 0;
  for (;;) {
    asm volatile("global_load_dwordx4 %0, %2, off sc1\n\t"
                 "global_load_dwordx4 %1, %3, off sc1\n\t"
                 "s_waitcnt vmcnt(0)"
                 : "=v"(a), "=v"(b) : "v"(q0), "v"(q1) : "memory");
    if (__all(a.y == g && a.w == g && b.y == g && b.w == g)) return;
    if (++spins > 4096) {
      const u64 c0 = ld_rec(q0), c1 = ld_rec(q0 + 1);
      const u64 c2 = ld_rec(q1), c3 = ld_rec(q1 + 1);
      a.x = (unsigned)c0; a.y = (unsigned)(c0 >> 32);
      a.z = (unsigned)c1; a.w = (unsigned)(c1 >> 32);
      b.x = (unsigned)c2; b.y = (unsigned)(c2 >> 32);
      b.z = (unsigned)c3; b.w = (unsigned)(c3 >> 32);
      if (__all(a.y == g && a.w == g && b.y == g && b.w == g)) return;
    }
    __builtin_amdgcn_s_sleep(1);
  }
}

// verify-read 4 contiguous records and deposit values to LDS
__device__ __forceinline__ void poll4c(const u64* __restrict__ base, int i4,
                                       unsigned g, float* __restrict__ lds) {
  uint4 a, b;
  poll_pair(base + i4, base + i4 + 2, g, a, b);
  float4 out;
  out.x = __uint_as_float(a.x);
  out.y = __uint_as_float(a.z);
  out.z = __uint_as_float(b.x);
  out.w = __uint_as_float(b.z);
  *(float4*)(lds + i4) = out;
}

// zero flags (16384 u32) + records (7168 u64 = 14336 u32) each launch
__global__ void init_sync(unsigned* f) {
  #pragma unroll
  for (int i = 0; i < 120; ++i) f[i * 256 + threadIdx.x] = 0u;
}

// fp32 -> bf16 LINEAR pack (row layout preserved, u32 = 2 adjacent bf16)
__global__ __launch_bounds__(256) void pack_lin(
    const float* __restrict__ src, unsigned* __restrict__ dst,
    int src_ld, int lc, size_t total_u32)
{
  for (size_t u = (size_t)blockIdx.x * 256 + threadIdx.x; u < total_u32;
       u += (size_t)gridDim.x * 256) {
    const size_t pos = u * 2;
    const size_t row = pos >> lc;
    const int    col = (int)(pos & (((size_t)1 << lc) - 1));
    const float2 v = *(const float2*)(src + row * src_ld + col);
    dst[u] = (unsigned)f2bf_rne(v.x) | ((unsigned)f2bf_rne(v.y) << 16);
  }
}

// fp32 -> bf16 pack with per-512-chunk column swizzle (register-resident dots)
__global__ __launch_bounds__(256) void pack_swz(
    const float* __restrict__ src, unsigned* __restrict__ dst,
    int src_ld, int lc, size_t total2)
{
  for (size_t u = (size_t)blockIdx.x * 256 + threadIdx.x; u < total2;
       u += (size_t)gridDim.x * 256) {
    const size_t pos = u * 2;
    const size_t row = pos >> lc;
    const int pcol  = (int)(pos & (((size_t)1 << lc) - 1));
    const int chunk = pcol >> 9;
    const int off   = pcol & 511;
    const int l     = off >> 3;
    const int p     = (off >> 1) & 3;
    const float2 v  = *(const float2*)(src + row * src_ld + chunk * 512 + p * 128 + l * 2);
    dst[u] = (unsigned)f2bf_rne(v.x) | ((unsigned)f2bf_rne(v.y) << 16);
  }
}

__device__ __forceinline__ float chunk_dot(const uint4 w, const float* vchunk, int lane) {
  float acc = 0.f; float2 p, a;
  a = *(const float2*)(vchunk + lane * 2 +   0); p = bf2(w.x); acc += p.x*a.x + p.y*a.y;
  a = *(const float2*)(vchunk + lane * 2 + 128); p = bf2(w.y); acc += p.x*a.x + p.y*a.y;
  a = *(const float2*)(vchunk + lane * 2 + 256); p = bf2(w.z); acc += p.x*a.x + p.y*a.y;
  a = *(const float2*)(vchunk + lane * 2 + 384); p = bf2(w.w); acc += p.x*a.x + p.y*a.y;
  return acc;
}

__global__ __launch_bounds__(NTHR) void rssm_seq(
    const float* __restrict__ pre_act, const float* __restrict__ pre_e,
    unsigned* __restrict__ flags,            // 4 x 256 x 16 u32 (64B-padded per WG)
    u64* __restrict__ rec_s,                 // 1024 stoch records
    u64* __restrict__ rec_x,  u64* __restrict__ rec_d, u64* __restrict__ rec_q,
    const unsigned* __restrict__ wps_lin,   // [2048][512 u32]
    const unsigned* __restrict__ wih_lin,   // [6144][1024 u32]
    const ushort_t* __restrict__ whh_swz,   // [6144][2048] swizzled
    const ushort_t* __restrict__ wqe_swz,   // [2048][2048] swizzled
    const ushort_t* __restrict__ wqd_swz,   // [2048][2048] swizzled
    const float* __restrict__ gru_b, const float* __restrict__ gru_bn,
    const float* __restrict__ q_dec_b, const float* __restrict__ noise,
    float* __restrict__ stoch_out, float* __restrict__ det_out,
    float* __restrict__ qmu_out, float* __restrict__ qstd_out)
{
  // ---- 140 KB static LDS: forces 1 WG/CU -> large RA budget (verified R8: 128 VGPR) ----
  __shared__ float    xs[2048];
  __shared__ float    ds[2048];          // det_prev -> det_t (persists across steps)
  __shared__ float    qs[2048];
  __shared__ float    sp[1024];
  __shared__ float    part4[8];
  __shared__ unsigned wps_l[8 * 512];    // 16 KB stage-1 weights
  __shared__ unsigned wih_l[24 * 1024];  // 96 KB GRU ih weights

  const int tid  = threadIdx.x;
  const int wv   = tid >> 6;
  const int lane = tid & 63;
  const int bid  = blockIdx.x;
  const int r0   = bid * 8;
  unsigned* flag1 = flags;
  unsigned* flag2 = flags + 256 * 16;
  unsigned* flag3 = flags + 512 * 16;
  unsigned* flag4 = flags + 768 * 16;

  // ------------- one-time LDS weight fill -------------
  #pragma unroll
  for (int i = 0; i < 8; ++i) {
    const int idx = i * NTHR + tid;
    const int row = idx >> 9, u = idx & 511;
    wps_l[idx] = wps_lin[((size_t)(r0 + row) << 9) | u];
  }
  #pragma unroll
  for (int i = 0; i < 48; ++i) {
    const int idx = i * NTHR + tid;
    const int gr = idx >> 10, u = idx & 1023;
    const int g = gr >> 3, rr = gr & 7;
    wih_l[idx] = wih_lin[((size_t)(g * 2048 + r0 + rr) << 10) | u];
  }

  // ------------- pinned register weights (volatile loads, swizzled layout) -------------
  uint4 w2h[12];   // GRU hh: 3 gates x 4 chunks for row r0+wv
  uint4 w3[4];     // wqe row r0+wv
  uint4 w4[4];     // wqd dot wv
  {
    const size_t i = (size_t)(r0 + wv);
    #pragma unroll
    for (int g = 0; g < 3; ++g) {
      const uint4* wr = (const uint4*)(whh_swz + (i + (size_t)g * 2048) * 2048);
      #pragma unroll
      for (int c = 0; c < 4; ++c) LD_PIN_U4(w2h[g * 4 + c], wr + c * 64 + lane);
    }
    const uint4* we = (const uint4*)(wqe_swz + i * 2048);
    #pragma unroll
    for (int c = 0; c < 4; ++c) LD_PIN_U4(w3[c], we + c * 64 + lane);
    const int jg = bid * 4 + (wv & 3), sel = wv >> 2;
    const uint4* wd = (const uint4*)(wqd_swz + (size_t)(jg + sel * 1024) * 2048);
    #pragma unroll
    for (int c = 0; c < 4; ++c) LD_PIN_U4(w4[c], wd + c * 64 + lane);
    asm volatile("s_waitcnt vmcnt(0)" ::: "memory");
  }

  // per-wave constants
  float gb_r = 0.f, gb_z = 0.f, gb_n = 0.f, gbn = 0.f;
  if (lane == 0) {
    gb_r = gru_b[r0 + wv];
    gb_z = gru_b[r0 + wv + 2048];
    gb_n = gru_b[r0 + wv + 4096];
    gbn  = gru_bn[r0 + wv];
  }
  float qdb_m = 0.f, qdb_s = 0.f;
  if (tid < 4) {
    qdb_m = q_dec_b[bid * 4 + tid];
    qdb_s = q_dec_b[bid * 4 + tid + 1024];
  }

  // zero initial state
  if (tid < 256) ((float4*)sp)[tid] = float4{0.f, 0.f, 0.f, 0.f};
  ((float4*)ds)[tid] = float4{0.f, 0.f, 0.f, 0.f};
  __syncthreads();

  for (int t = 0; t < T_STEPS; ++t) {
    const unsigned gb  = (unsigned)(t * 4);
    const unsigned gen = (unsigned)(t + 1);
    float pa = 0.f, pe = 0.f;
    if (lane == 0) {
      pa = pre_act[(size_t)t * D_DIM + r0 + wv];
      pe = pre_e  [(size_t)t * H_DIM + r0 + wv];
    }

    // ======== stage-1 input: stoch(t-1) — detect flag4, verify bulk ========
    if (t > 0) {
      if (wv == 0) poll_flags(flag4, (unsigned)t, lane);
      __syncthreads();
      if (tid < 256) poll4c(rec_s, 4 * tid, gb, sp);
    }
    __syncthreads();

    // ======== stage 1: x = elu(Wps @ stoch_prev + pre_act[t]) ========
    {
      const unsigned* wrow = wps_l + (wv << 9);
      float acc = 0.f;
      #pragma unroll
      for (int c = 0; c < 2; ++c)
        #pragma unroll
        for (int p = 0; p < 4; ++p) {
          const float2 a = *(const float2*)(sp + c * 512 + p * 128 + lane * 2);
          const float2 w = bf2(wrow[c * 256 + p * 64 + lane]);
          acc += w.x * a.x + w.y * a.y;
        }
      acc = wave_reduce(acc);
      if (lane == 0) st_rec(rec_x + r0 + wv, eluf(acc + pa), gb + 1);   // no drain
    }
    __syncthreads();                       // all record stores issued
    if (tid == 0) st_flag(flag1 + bid * 16, gen);

    // ======== stage 2A: hh dots (det_prev in LDS) — overlaps the x exchange ========
    float h0 = 0.f, h1 = 0.f, h2 = 0.f;
    #pragma unroll
    for (int c = 0; c < 4; ++c) {
      #pragma unroll
      for (int p = 0; p < 4; ++p) {
        const float2 dvv = *(const float2*)(ds + c * 512 + p * 128 + lane * 2);
        const unsigned u0 = (p == 0) ? w2h[c].x     : (p == 1) ? w2h[c].y     : (p == 2) ? w2h[c].z     : w2h[c].w;
        const unsigned u1 = (p == 0) ? w2h[4 + c].x : (p == 1) ? w2h[4 + c].y : (p == 2) ? w2h[4 + c].z : w2h[4 + c].w;
        const unsigned u2 = (p == 0) ? w2h[8 + c].x : (p == 1) ? w2h[8 + c].y : (p == 2) ? w2h[8 + c].z : w2h[8 + c].w;
        float2 w;
        w = bf2(u0); h0 += w.x * dvv.x + w.y * dvv.y;
        w = bf2(u1); h1 += w.x * dvv.x + w.y * dvv.y;
        w = bf2(u2); h2 += w.x * dvv.x + w.y * dvv.y;
      }
    }
    h0 = wave_reduce(h0); h1 = wave_reduce(h1); h2 = wave_reduce(h2);

    // ======== stage 2B: detect x, verify bulk, ih dots ========
    if (wv == 0) poll_flags(flag1, gen, lane);
    __syncthreads();
    poll4c(rec_x, 4 * tid, gb + 1, xs);
    __syncthreads();
    {
      const unsigned* wg0 = wih_l + wv * 1024;
      const unsigned* wg1 = wg0 + 8192;
      const unsigned* wg2 = wg1 + 8192;
      float a0 = 0.f, a1 = 0.f, a2 = 0.f;
      #pragma unroll
      for (int c = 0; c < 4; ++c) {
        #pragma unroll
        for (int p = 0; p < 4; ++p) {
          const float2 xvv = *(const float2*)(xs + c * 512 + p * 128 + lane * 2);
          const int wi = c * 256 + p * 64 + lane;
          float2 w;
          w = bf2(wg0[wi]); a0 += w.x * xvv.x + w.y * xvv.y;
          w = bf2(wg1[wi]); a1 += w.x * xvv.x + w.y * xvv.y;
          w = bf2(wg2[wi]); a2 += w.x * xvv.x + w.y * xvv.y;
        }
      }
      a0 = wave_reduce(a0); a1 = wave_reduce(a1); a2 = wave_reduce(a2);
      if (lane == 0) {
        const float r_ = sigmoidf_(a0 + gb_r + h0);
        const float z_ = sigmoidf_(a1 + gb_z + h1);
        const float n_ = tanhf(a2 + gb_n + r_ * (h2 + gbn));
        const float det_v = n_ + z_ * (ds[r0 + wv] - n_);
        st_rec(rec_d + r0 + wv, det_v, gb + 2);                         // no drain
        det_out[(size_t)t * D_DIM + r0 + wv] = det_v;   // plain cached (output only)
      }
    }
    __syncthreads();   // record stores issued + all waves done reading ds
    if (tid == 0) st_flag(flag2 + bid * 16, gen);

    // ======== stage 3: detect det, verify bulk (overwrites ds), compute q ========
    if (wv == 0) poll_flags(flag2, gen, lane);
    __syncthreads();
    poll4c(rec_d, 4 * tid, gb + 2, ds);
    __syncthreads();
    {
      float acc = 0.f;
      #pragma unroll
      for (int c = 0; c < 4; ++c) acc += chunk_dot(w3[c], ds + c * 512, lane);
      acc = wave_reduce(acc);
      if (lane == 0) st_rec(rec_q + r0 + wv, eluf(acc + pe), gb + 3);   // no drain
    }
    __syncthreads();
    if (tid == 0) st_flag(flag3 + bid * 16, gen);

    // ======== stage 4: detect q, verify bulk, posterior head + fused stoch ========
    if (wv == 0) poll_flags(flag3, gen, lane);
    __syncthreads();
    poll4c(rec_q, 4 * tid, gb + 3, qs);
    __syncthreads();
    {
      float acc = 0.f;
      #pragma unroll
      for (int c = 0; c < 4; ++c) acc += chunk_dot(w4[c], qs + c * 512, lane);
      acc = wave_reduce(acc);
      if (lane == 0) part4[wv] = acc;
    }
    __syncthreads();
    if (tid < 4) {
      const int j = bid * 4 + tid;
      const float qm  = part4[tid] + qdb_m;
      const float qsd = softplusf(part4[tid + 4] + qdb_s) + 0.1f;
      const float sv  = qm + qsd * noise[(size_t)t * S_DIM + j];
      qmu_out  [(size_t)t * S_DIM + j] = qm;    // plain cached (outputs only)
      qstd_out [(size_t)t * S_DIM + j] = qsd;
      stoch_out[(size_t)t * S_DIM + j] = sv;
      st_rec(rec_s + j, sv, gb + 4);            // lanes 0-3 of wave 0
    }
    if (wv == 0 && lane == 0) st_flag(flag4 + bid * 16, gen);  // same wave: issue order ok
    // no trailing barrier: next step's flag4 poll + verify is the join
  }
}

// C[m,n] = act( sum_k Xc[m,k] * W[n*ldw + woff + k] + bias[n] )
// 128x64 tile, 256 threads, 8x4 outputs/thread, float4 global + LDS reads.
template <int ACT>
__global__ __launch_bounds__(256) void gemm_xwT(
    const float* __restrict__ X1, int ldx1,
    const float* __restrict__ X2, int ldx2, int ksplit,
    const float* __restrict__ W, int ldw, int woff,
    const float* __restrict__ bias,
    float* __restrict__ C, int ldc,
    int M, int N, int K)
{
  __shared__ float Xs[16][132];   // [k][m], padded
  __shared__ float Ws[16][68];    // [k][n], padded
  const int tid = threadIdx.x;
  const int tx = tid & 15;        // n-group (4 cols each)
  const int ty = tid >> 4;        // m-group (8 rows each)
  const int m0 = blockIdx.y * 128, n0 = blockIdx.x * 64;
  const int xrow = tid >> 1;           // 0..127
  const int xk8  = (tid & 1) * 8;      // 0 or 8
  const int wrow = tid & 63;           // 0..63
  const int wk4  = (tid >> 6) * 4;     // 0,4,8,12
  float acc[8][4] = {};
  for (int k0 = 0; k0 < K; k0 += 16) {
    {
      const int m = m0 + xrow;
      #pragma unroll
      for (int q = 0; q < 2; ++q) {
        const int k = k0 + xk8 + q * 4;
        float4 v = float4{0.f, 0.f, 0.f, 0.f};
        if (m < M) {
          v = (k < ksplit) ? *(const float4*)(X1 + (size_t)m * ldx1 + k)
                           : *(const float4*)(X2 + (size_t)m * ldx2 + (k - ksplit));
        }
        Xs[xk8 + q * 4 + 0][xrow] = v.x;
        Xs[xk8 + q * 4 + 1][xrow] = v.y;
        Xs[xk8 + q * 4 + 2][xrow] = v.z;
        Xs[xk8 + q * 4 + 3][xrow] = v.w;
      }
      const int n = n0 + wrow;
      float4 wv = float4{0.f, 0.f, 0.f, 0.f};
      if (n < N) wv = *(const float4*)(W + (size_t)n * ldw + woff + k0 + wk4);
      Ws[wk4 + 0][wrow] = wv.x;
      Ws[wk4 + 1][wrow] = wv.y;
      Ws[wk4 + 2][wrow] = wv.z;
      Ws[wk4 + 3][wrow] = wv.w;
    }
    __syncthreads();
    #pragma unroll
    for (int kk = 0; kk < 16; ++kk) {
      const float4 a0 = *(const float4*)(&Xs[kk][ty * 8]);
      const float4 a1 = *(const float4*)(&Xs[kk][ty * 8 + 4]);
      const float4 b  = *(const float4*)(&Ws[kk][tx * 4]);
      const float av[8] = {a0.x, a0.y, a0.z, a0.w, a1.x, a1.y, a1.z, a1.w};
      const float bv[4] = {b.x, b.y, b.z, b.w};
      #pragma unroll
      for (int i = 0; i < 8; ++i)
        #pragma unroll
        for (int j = 0; j < 4; ++j)
          acc[i][j] += av[i] * bv[j];
    }
    __syncthreads();
  }
  #pragma unroll
  for (int i = 0; i < 8; ++i) {
    const int m = m0 + ty * 8 + i;
    if (m >= M) continue;
    #pragma unroll
    for (int j = 0; j < 4; ++j) {
      const int n = n0 + tx * 4 + j;
      if (n >= N) continue;
      float v = acc[i][j] + bias[n];
      if (ACT == 1) v = eluf(v);
      if (ACT == 2) {
        if (n < 1024) C[(size_t)m * 1024 + n] = v;
        else          C[(size_t)m * 1024 + (n - 1024) + 1024 * 1024] = softplusf(v) + 0.1f;
      } else {
        C[(size_t)m * ldc + n] = v;
      }
    }
  }
}

extern "C" void kernel_launch(void* const* d_in, const int* in_sizes, int n_in,
                              void* d_out, int out_size, void* d_ws, size_t ws_size,
                              hipStream_t stream)
{
  const float* obs      = (const float*)d_in[0];
  const float* acts     = (const float*)d_in[1];
  const float* noise    = (const float*)d_in[2];
  const float* enc_w    = (const float*)d_in[3];
  const float* enc_b    = (const float*)d_in[4];
  const float* dec_w    = (const float*)d_in[5];
  const float* dec_b    = (const float*)d_in[6];
  const float* p_enc_w  = (const float*)d_in[7];
  const float* p_enc_b  = (const float*)d_in[8];
  const float* gru_wih  = (const float*)d_in[9];
  const float* gru_whh  = (const float*)d_in[10];
  const float* gru_b    = (const float*)d_in[11];
  const float* gru_bn   = (const float*)d_in[12];
  const float* p_dec1_w = (const float*)d_in[13];
  const float* p_dec1_b = (const float*)d_in[14];
  const float* p_dec2_w = (const float*)d_in[15];
  const float* p_dec2_b = (const float*)d_in[16];
  const float* q_enc_w  = (const float*)d_in[17];
  const float* q_enc_b  = (const float*)d_in[18];
  const float* q_dec_w  = (const float*)d_in[19];
  const float* q_dec_b  = (const float*)d_in[20];

  float* out   = (float*)d_out;
  float* stoch = out;                     // [1024,1024]
  float* det   = out + 1048576;           // [1024,2048]
  float* outs  = out + 3145728;           // [1024,1026] — dead during scan; hosts sync data
  float* qmu   = out + 4196352;           // [1024,1024]
  float* qstd  = out + 5244928;           // [1024,1024]
  float* pmu   = out + 6293504;           // [1024,1024] (pstd adjacent)

  // sync structures in the (scan-dead) outs region; final GEMM overwrites it fully.
  unsigned* flags = (unsigned*)outs;      // 4 x 256 x 16 u32 = 64 KB
  u64* rec_s = (u64*)(outs + 16384);      // 1024
  u64* rec_x = rec_s + 1024;              // 2048
  u64* rec_d = rec_x + 2048;              // 2048
  u64* rec_q = rec_d + 2048;              // 2048  (flags+recs ≈ 121 KB << outs size)

  float* ws       = (float*)d_ws;
  float* pre_act  = ws;                          // 2,097,152 f
  float* pre_e    = ws + 2097152;                // 2,097,152 f
  float* emb      = ws + 4194304;                // 2,097,152 f
  ushort_t* wpack = (ushort_t*)(ws + 6299648);
  ushort_t* wps_lin = wpack;                     //  2,097,152 us (LDS-dest, linear)
  ushort_t* wih_lin = wps_lin + 2097152;         // 12,582,912 us (LDS-dest, linear)
  ushort_t* whh_swz = wih_lin + 12582912;        // 12,582,912 us (reg-dest, swz)
  ushort_t* wqe_swz = whh_swz + 12582912;        //  4,194,304 us (reg-dest, swz)
  ushort_t* wqd_swz = wqe_swz + 4194304;         //  4,194,304 us (reg-dest, swz)

  init_sync<<<dim3(1), dim3(256), 0, stream>>>(flags);

  pack_lin<<<dim3(1024), dim3(256), 0, stream>>>(p_enc_w, (unsigned*)wps_lin, 1088, 10, 1048576);
  pack_lin<<<dim3(1024), dim3(256), 0, stream>>>(gru_wih, (unsigned*)wih_lin, 2048, 11, 6291456);
  pack_swz<<<dim3(1024), dim3(256), 0, stream>>>(gru_whh, (unsigned*)whh_swz, 2048, 11, 6291456);
  pack_swz<<<dim3(1024), dim3(256), 0, stream>>>(q_enc_w, (unsigned*)wqe_swz, 4096, 11, 2097152);
  pack_swz<<<dim3(1024), dim3(256), 0, stream>>>(q_dec_w, (unsigned*)wqd_swz, 2048, 11, 2097152);

  dim3 blk(256);
  gemm_xwT<0><<<dim3(32, 8), blk, 0, stream>>>(
      acts, 64, acts, 64, 64, p_enc_w, 1088, 1024, p_enc_b, pre_act, 2048, 1024, 2048, 64);
  gemm_xwT<1><<<dim3(32, 8), blk, 0, stream>>>(
      obs, 1024, obs, 1024, 1024, enc_w, 1024, 0, enc_b, emb, 2048, 1024, 2048, 1024);
  gemm_xwT<0><<<dim3(32, 8), blk, 0, stream>>>(
      emb, 2048, emb, 2048, 2048, q_enc_w, 4096, 2048, q_enc_b, pre_e, 2048, 1024, 2048, 2048);

  rssm_seq<<<dim3(NWG), dim3(NTHR), 0, stream>>>(
      pre_act, pre_e, flags, rec_s, rec_x, rec_d, rec_q,
      (const unsigned*)wps_lin, (const unsigned*)wih_lin,
      whh_swz, wqe_swz, wqd_swz,
      gru_b, gru_bn, q_dec_b, noise, stoch, det, qmu, qstd);

  gemm_xwT<1><<<dim3(32, 8), blk, 0, stream>>>(
      det, 2048, det, 2048, 2048, p_dec1_w, 2048, 0, p_dec1_b, emb, 2048, 1024, 2048, 2048);
  gemm_xwT<2><<<dim3(32, 8), blk, 0, stream>>>(
      emb, 2048, emb, 2048, 2048, p_dec2_w, 2048, 0, p_dec2_b, pmu, 1024, 1024, 2048, 2048);
  gemm_xwT<0><<<dim3(17, 8), blk, 0, stream>>>(
      stoch, 1024, det, 2048, 1024, dec_w, 3072, 0, dec_b, outs, 1026, 1024, 1026, 3072);
}

// Round 19
// 17164.339 us; speedup vs baseline: 1.0490x; 1.0490x over previous
//
#include <hip/hip_runtime.h>
#include <cstdint>
#include <cstddef>

#define T_STEPS 1024
#define S_DIM   1024
#define A_DIM   64
#define D_DIM   2048
#define H_DIM   2048
#define NWG     256
#define NTHR    512    // 8 waves per WG, 1 WG per CU (forced by 140KB LDS)

typedef unsigned short ushort_t;

__device__ __forceinline__ float eluf(float v)      { return v > 0.f ? v : expm1f(v); }
__device__ __forceinline__ float softplusf(float v) { return v > 20.f ? v : log1pf(expf(v)); }
__device__ __forceinline__ float sigmoidf_(float v) { return 1.f / (1.f + expf(-v)); }

__device__ __forceinline__ float wave_reduce(float v) {
  #pragma unroll
  for (int off = 32; off > 0; off >>= 1) v += __shfl_xor(v, off, 64);
  return v;
}

__device__ __forceinline__ float2 bf2(unsigned u) {
  float2 r;
  r.x = __uint_as_float(u << 16);
  r.y = __uint_as_float(u & 0xffff0000u);
  return r;
}
__device__ __forceinline__ ushort_t f2bf_rne(float f) {
  unsigned u = __float_as_uint(f);
  u += 0x7fffu + ((u >> 16) & 1u);
  return (ushort_t)(u >> 16);
}

// pinned (volatile) weight load: cannot be rematerialized/sunk into the loop.
#define LD_PIN_U4(dst, addr) \
  asm volatile("global_load_dwordx4 %0, %1, off" : "=v"(dst) : "v"(addr))

// ---- agent-scope (MALL-coherent) plain value / flag stores
__device__ __forceinline__ void st_val(float* p, float v) {
  __hip_atomic_store((unsigned*)p, __float_as_uint(v),
                     __ATOMIC_RELAXED, __HIP_MEMORY_SCOPE_AGENT);
}
__device__ __forceinline__ void st_flag(unsigned* p, unsigned g) {
  __hip_atomic_store(p, g, __ATOMIC_RELAXED, __HIP_MEMORY_SCOPE_AGENT);
}

// Wave-0 poll of 256 per-WG flags, each on its own 64B line (stride 16 u32).
// 4 batched dword loads per lane, one vmcnt per iteration; sc1 = agent scope
// (R12-verified). No RMW, no shared hot line (R13 lesson).
__device__ __forceinline__ void poll_flags(const unsigned* f, unsigned g, int lane) {
  const unsigned* p0 = f + (lane * 4 + 0) * 16;
  const unsigned* p1 = f + (lane * 4 + 1) * 16;
  const unsigned* p2 = f + (lane * 4 + 2) * 16;
  const unsigned* p3 = f + (lane * 4 + 3) * 16;
  for (;;) {
    unsigned a, b, c, d;
    asm volatile("global_load_dword %0, %4, off sc1\n\t"
                 "global_load_dword %1, %5, off sc1\n\t"
                 "global_load_dword %2, %6, off sc1\n\t"
                 "global_load_dword %3, %7, off sc1\n\t"
                 "s_waitcnt vmcnt(0)"
                 : "=v"(a), "=v"(b), "=v"(c), "=v"(d)
                 : "v"(p0), "v"(p1), "v"(p2), "v"(p3) : "memory");
    if (__all(a >= g && b >= g && c >= g && d >= g)) return;
    __builtin_amdgcn_s_sleep(1);
  }
}

// one-shot bulk read of 4 contiguous floats (agent scope) -> LDS
__device__ __forceinline__ void bulk4(const float* __restrict__ src, int i4,
                                      float* __restrict__ lds) {
  float4 v;
  asm volatile("global_load_dwordx4 %0, %1, off sc1\n\ts_waitcnt vmcnt(0)"
               : "=v"(v) : "v"(src + i4) : "memory");
  *(float4*)(lds + i4) = v;
}

// zero the flag region: 4 stages x 256 WGs x 16 u32 = 16384 u32 (kills 0xAA poison)
__global__ void init_flags(unsigned* f) {
  #pragma unroll
  for (int i = 0; i < 64; ++i) f[i * 256 + threadIdx.x] = 0u;
}

// fp32 -> bf16 LINEAR pack (row layout preserved, u32 = 2 adjacent bf16)
__global__ __launch_bounds__(256) void pack_lin(
    const float* __restrict__ src, unsigned* __restrict__ dst,
    int src_ld, int lc, size_t total_u32)
{
  for (size_t u = (size_t)blockIdx.x * 256 + threadIdx.x; u < total_u32;
       u += (size_t)gridDim.x * 256) {
    const size_t pos = u * 2;
    const size_t row = pos >> lc;
    const int    col = (int)(pos & (((size_t)1 << lc) - 1));
    const float2 v = *(const float2*)(src + row * src_ld + col);
    dst[u] = (unsigned)f2bf_rne(v.x) | ((unsigned)f2bf_rne(v.y) << 16);
  }
}

// fp32 -> bf16 pack with per-512-chunk column swizzle (register-resident dots)
__global__ __launch_bounds__(256) void pack_swz(
    const float* __restrict__ src, unsigned* __restrict__ dst,
    int src_ld, int lc, size_t total2)
{
  for (size_t u = (size_t)blockIdx.x * 256 + threadIdx.x; u < total2;
       u += (size_t)gridDim.x * 256) {
    const size_t pos = u * 2;
    const size_t row = pos >> lc;
    const int pcol  = (int)(pos & (((size_t)1 << lc) - 1));
    const int chunk = pcol >> 9;
    const int off   = pcol & 511;
    const int l     = off >> 3;
    const int p     = (off >> 1) & 3;
    const float2 v  = *(const float2*)(src + row * src_ld + chunk * 512 + p * 128 + l * 2);
    dst[u] = (unsigned)f2bf_rne(v.x) | ((unsigned)f2bf_rne(v.y) << 16);
  }
}

__device__ __forceinline__ float chunk_dot(const uint4 w, const float* vchunk, int lane) {
  float acc = 0.f; float2 p, a;
  a = *(const float2*)(vchunk + lane * 2 +   0); p = bf2(w.x); acc += p.x*a.x + p.y*a.y;
  a = *(const float2*)(vchunk + lane * 2 + 128); p = bf2(w.y); acc += p.x*a.x + p.y*a.y;
  a = *(const float2*)(vchunk + lane * 2 + 256); p = bf2(w.z); acc += p.x*a.x + p.y*a.y;
  a = *(const float2*)(vchunk + lane * 2 + 384); p = bf2(w.w); acc += p.x*a.x + p.y*a.y;
  return acc;
}

__global__ __launch_bounds__(NTHR) void rssm_seq(
    const float* __restrict__ pre_act, const float* __restrict__ pre_e,
    unsigned* __restrict__ flags,            // 4 x 256 x 16 u32 (64B-padded per WG)
    float* __restrict__ sv_vals,             // 1024 stoch values
    float* __restrict__ xv,  float* __restrict__ dv, float* __restrict__ qv,
    const unsigned* __restrict__ wps_lin,   // [2048][512 u32]
    const unsigned* __restrict__ wih_lin,   // [6144][1024 u32]
    const ushort_t* __restrict__ whh_swz,   // [6144][2048] swizzled
    const ushort_t* __restrict__ wqe_swz,   // [2048][2048] swizzled
    const ushort_t* __restrict__ wqd_swz,   // [2048][2048] swizzled
    const float* __restrict__ gru_b, const float* __restrict__ gru_bn,
    const float* __restrict__ q_dec_b, const float* __restrict__ noise,
    float* __restrict__ stoch_out, float* __restrict__ det_out,
    float* __restrict__ qmu_out, float* __restrict__ qstd_out)
{
  // ---- 140 KB static LDS: forces 1 WG/CU -> large RA budget (verified R8: 128 VGPR) ----
  __shared__ float    xs[2048];
  __shared__ float    ds[2048];          // det_prev -> det_t (persists across steps)
  __shared__ float    qs[2048];
  __shared__ float    sp[1024];
  __shared__ float    part4[8];
  __shared__ unsigned wps_l[8 * 512];    // 16 KB stage-1 weights
  __shared__ unsigned wih_l[24 * 1024];  // 96 KB GRU ih weights

  const int tid  = threadIdx.x;
  const int wv   = tid >> 6;
  const int lane = tid & 63;
  const int bid  = blockIdx.x;
  const int r0   = bid * 8;
  unsigned* flag1 = flags;
  unsigned* flag2 = flags + 256 * 16;
  unsigned* flag3 = flags + 512 * 16;
  unsigned* flag4 = flags + 768 * 16;

  // ------------- one-time LDS weight fill -------------
  #pragma unroll
  for (int i = 0; i < 8; ++i) {
    const int idx = i * NTHR + tid;
    const int row = idx >> 9, u = idx & 511;
    wps_l[idx] = wps_lin[((size_t)(r0 + row) << 9) | u];
  }
  #pragma unroll
  for (int i = 0; i < 48; ++i) {
    const int idx = i * NTHR + tid;
    const int gr = idx >> 10, u = idx & 1023;
    const int g = gr >> 3, rr = gr & 7;
    wih_l[idx] = wih_lin[((size_t)(g * 2048 + r0 + rr) << 10) | u];
  }

  // ------------- pinned register weights (volatile loads, swizzled layout) -------------
  uint4 w2h[12];   // GRU hh: 3 gates x 4 chunks for row r0+wv
  uint4 w3[4];     // wqe row r0+wv
  uint4 w4[4];     // wqd dot wv
  {
    const size_t i = (size_t)(r0 + wv);
    #pragma unroll
    for (int g = 0; g < 3; ++g) {
      const uint4* wr = (const uint4*)(whh_swz + (i + (size_t)g * 2048) * 2048);
      #pragma unroll
      for (int c = 0; c < 4; ++c) LD_PIN_U4(w2h[g * 4 + c], wr + c * 64 + lane);
    }
    const uint4* we = (const uint4*)(wqe_swz + i * 2048);
    #pragma unroll
    for (int c = 0; c < 4; ++c) LD_PIN_U4(w3[c], we + c * 64 + lane);
    const int jg = bid * 4 + (wv & 3), sel = wv >> 2;
    const uint4* wd = (const uint4*)(wqd_swz + (size_t)(jg + sel * 1024) * 2048);
    #pragma unroll
    for (int c = 0; c < 4; ++c) LD_PIN_U4(w4[c], wd + c * 64 + lane);
    asm volatile("s_waitcnt vmcnt(0)" ::: "memory");
  }

  // per-wave constants
  float gb_r = 0.f, gb_z = 0.f, gb_n = 0.f, gbn = 0.f;
  if (lane == 0) {
    gb_r = gru_b[r0 + wv];
    gb_z = gru_b[r0 + wv + 2048];
    gb_n = gru_b[r0 + wv + 4096];
    gbn  = gru_bn[r0 + wv];
  }
  float qdb_m = 0.f, qdb_s = 0.f;
  if (tid < 4) {
    qdb_m = q_dec_b[bid * 4 + tid];
    qdb_s = q_dec_b[bid * 4 + tid + 1024];
  }

  // zero initial state
  if (tid < 256) ((float4*)sp)[tid] = float4{0.f, 0.f, 0.f, 0.f};
  ((float4*)ds)[tid] = float4{0.f, 0.f, 0.f, 0.f};
  __syncthreads();

  for (int t = 0; t < T_STEPS; ++t) {
    const unsigned gen = (unsigned)(t + 1);
    float pa = 0.f, pe = 0.f;
    if (lane == 0) {
      pa = pre_act[(size_t)t * D_DIM + r0 + wv];
      pe = pre_e  [(size_t)t * H_DIM + r0 + wv];
    }

    // ======== stage-1 input: stoch(t-1) ========
    if (t > 0) {
      if (wv == 0) poll_flags(flag4, (unsigned)t, lane);
      __syncthreads();
      if (tid < 256) bulk4(sv_vals, 4 * tid, sp);
    }
    __syncthreads();

    // ======== stage 1: x = elu(Wps @ stoch_prev + pre_act[t]) ========
    {
      const unsigned* wrow = wps_l + (wv << 9);
      float acc = 0.f;
      #pragma unroll
      for (int c = 0; c < 2; ++c)
        #pragma unroll
        for (int p = 0; p < 4; ++p) {
          const float2 a = *(const float2*)(sp + c * 512 + p * 128 + lane * 2);
          const float2 w = bf2(wrow[c * 256 + p * 64 + lane]);
          acc += w.x * a.x + w.y * a.y;
        }
      acc = wave_reduce(acc);
      if (lane == 0) st_val(xv + r0 + wv, eluf(acc + pa));
      asm volatile("s_waitcnt vmcnt(0)" ::: "memory");   // release: data before flag
    }
    __syncthreads();
    if (tid == 0) st_flag(flag1 + bid * 16, gen);

    // ======== stage 2A: hh dots (det_prev in LDS) — overlaps the x exchange ========
    float h0 = 0.f, h1 = 0.f, h2 = 0.f;
    #pragma unroll
    for (int c = 0; c < 4; ++c) {
      #pragma unroll
      for (int p = 0; p < 4; ++p) {
        const float2 dvv = *(const float2*)(ds + c * 512 + p * 128 + lane * 2);
        const unsigned u0 = (p == 0) ? w2h[c].x     : (p == 1) ? w2h[c].y     : (p == 2) ? w2h[c].z     : w2h[c].w;
        const unsigned u1 = (p == 0) ? w2h[4 + c].x : (p == 1) ? w2h[4 + c].y : (p == 2) ? w2h[4 + c].z : w2h[4 + c].w;
        const unsigned u2 = (p == 0) ? w2h[8 + c].x : (p == 1) ? w2h[8 + c].y : (p == 2) ? w2h[8 + c].z : w2h[8 + c].w;
        float2 w;
        w = bf2(u0); h0 += w.x * dvv.x + w.y * dvv.y;
        w = bf2(u1); h1 += w.x * dvv.x + w.y * dvv.y;
        w = bf2(u2); h2 += w.x * dvv.x + w.y * dvv.y;
      }
    }
    h0 = wave_reduce(h0); h1 = wave_reduce(h1); h2 = wave_reduce(h2);

    // ======== stage 2B: detect x, bulk read, ih dots ========
    if (wv == 0) poll_flags(flag1, gen, lane);
    __syncthreads();
    bulk4(xv, 4 * tid, xs);
    __syncthreads();
    {
      const unsigned* wg0 = wih_l + wv * 1024;
      const unsigned* wg1 = wg0 + 8192;
      const unsigned* wg2 = wg1 + 8192;
      float a0 = 0.f, a1 = 0.f, a2 = 0.f;
      #pragma unroll
      for (int c = 0; c < 4; ++c) {
        #pragma unroll
        for (int p = 0; p < 4; ++p) {
          const float2 xvv = *(const float2*)(xs + c * 512 + p * 128 + lane * 2);
          const int wi = c * 256 + p * 64 + lane;
          float2 w;
          w = bf2(wg0[wi]); a0 += w.x * xvv.x + w.y * xvv.y;
          w = bf2(wg1[wi]); a1 += w.x * xvv.x + w.y * xvv.y;
          w = bf2(wg2[wi]); a2 += w.x * xvv.x + w.y * xvv.y;
        }
      }
      a0 = wave_reduce(a0); a1 = wave_reduce(a1); a2 = wave_reduce(a2);
      if (lane == 0) {
        const float r_ = sigmoidf_(a0 + gb_r + h0);
        const float z_ = sigmoidf_(a1 + gb_z + h1);
        const float n_ = tanhf(a2 + gb_n + r_ * (h2 + gbn));
        const float det_v = n_ + z_ * (ds[r0 + wv] - n_);
        st_val(dv + r0 + wv, det_v);
        det_out[(size_t)t * D_DIM + r0 + wv] = det_v;   // plain cached (output only)
      }
      asm volatile("s_waitcnt vmcnt(0)" ::: "memory");
    }
    __syncthreads();
    if (tid == 0) st_flag(flag2 + bid * 16, gen);

    // ======== stage 3: q = elu(Wqe @ det_t + pre_e[t]) ========
    if (wv == 0) poll_flags(flag2, gen, lane);
    __syncthreads();
    bulk4(dv, 4 * tid, ds);            // overwrites det_prev (all hh reads done)
    __syncthreads();
    {
      float acc = 0.f;
      #pragma unroll
      for (int c = 0; c < 4; ++c) acc += chunk_dot(w3[c], ds + c * 512, lane);
      acc = wave_reduce(acc);
      if (lane == 0) st_val(qv + r0 + wv, eluf(acc + pe));
      asm volatile("s_waitcnt vmcnt(0)" ::: "memory");
    }
    __syncthreads();
    if (tid == 0) st_flag(flag3 + bid * 16, gen);

    // ======== stage 4: posterior head, fused stoch production ========
    if (wv == 0) poll_flags(flag3, gen, lane);
    __syncthreads();
    bulk4(qv, 4 * tid, qs);
    __syncthreads();
    {
      float acc = 0.f;
      #pragma unroll
      for (int c = 0; c < 4; ++c) acc += chunk_dot(w4[c], qs + c * 512, lane);
      acc = wave_reduce(acc);
      if (lane == 0) part4[wv] = acc;
    }
    __syncthreads();
    if (tid < 4) {
      const int j = bid * 4 + tid;
      const float qm  = part4[tid] + qdb_m;
      const float qsd = softplusf(part4[tid + 4] + qdb_s) + 0.1f;
      const float sv  = qm + qsd * noise[(size_t)t * S_DIM + j];
      qmu_out  [(size_t)t * S_DIM + j] = qm;    // plain cached (outputs only)
      qstd_out [(size_t)t * S_DIM + j] = qsd;
      stoch_out[(size_t)t * S_DIM + j] = sv;
      st_val(sv_vals + j, sv);                  // the only cross-WG message
    }
    if (wv == 0) {
      asm volatile("s_waitcnt vmcnt(0)" ::: "memory");  // lanes 0-3 stores drained
      if (lane == 0) st_flag(flag4 + bid * 16, gen);
    }
    // no trailing barrier: next step's flag4 poll + syncthreads is the join
  }
}

// C[m,n] = act( sum_k Xc[m,k] * W[n*ldw + woff + k] + bias[n] )
// 128x64 tile, 256 threads, 8x4 outputs/thread, float4 global + LDS reads.
template <int ACT>
__global__ __launch_bounds__(256) void gemm_xwT(
    const float* __restrict__ X1, int ldx1,
    const float* __restrict__ X2, int ldx2, int ksplit,
    const float* __restrict__ W, int ldw, int woff,
    const float* __restrict__ bias,
    float* __restrict__ C, int ldc,
    int M, int N, int K)
{
  __shared__ float Xs[16][132];   // [k][m], padded
  __shared__ float Ws[16][68];    // [k][n], padded
  const int tid = threadIdx.x;
  const int tx = tid & 15;        // n-group (4 cols each)
  const int ty = tid >> 4;        // m-group (8 rows each)
  const int m0 = blockIdx.y * 128, n0 = blockIdx.x * 64;
  const int xrow = tid >> 1;           // 0..127
  const int xk8  = (tid & 1) * 8;      // 0 or 8
  const int wrow = tid & 63;           // 0..63
  const int wk4  = (tid >> 6) * 4;     // 0,4,8,12
  float acc[8][4] = {};
  for (int k0 = 0; k0 < K; k0 += 16) {
    {
      const int m = m0 + xrow;
      #pragma unroll
      for (int q = 0; q < 2; ++q) {
        const int k = k0 + xk8 + q * 4;
        float4 v = float4{0.f, 0.f, 0.f, 0.f};
        if (m < M) {
          v = (k < ksplit) ? *(const float4*)(X1 + (size_t)m * ldx1 + k)
                           : *(const float4*)(X2 + (size_t)m * ldx2 + (k - ksplit));
        }
        Xs[xk8 + q * 4 + 0][xrow] = v.x;
        Xs[xk8 + q * 4 + 1][xrow] = v.y;
        Xs[xk8 + q * 4 + 2][xrow] = v.z;
        Xs[xk8 + q * 4 + 3][xrow] = v.w;
      }
      const int n = n0 + wrow;
      float4 wv = float4{0.f, 0.f, 0.f, 0.f};
      if (n < N) wv = *(const float4*)(W + (size_t)n * ldw + woff + k0 + wk4);
      Ws[wk4 + 0][wrow] = wv.x;
      Ws[wk4 + 1][wrow] = wv.y;
      Ws[wk4 + 2][wrow] = wv.z;
      Ws[wk4 + 3][wrow] = wv.w;
    }
    __syncthreads();
    #pragma unroll
    for (int kk = 0; kk < 16; ++kk) {
      const float4 a0 = *(const float4*)(&Xs[kk][ty * 8]);
      const float4 a1 = *(const float4*)(&Xs[kk][ty * 8 + 4]);
      const float4 b  = *(const float4*)(&Ws[kk][tx * 4]);
      const float av[8] = {a0.x, a0.y, a0.z, a0.w, a1.x, a1.y, a1.z, a1.w};
      const float bv[4] = {b.x, b.y, b.z, b.w};
      #pragma unroll
      for (int i = 0; i < 8; ++i)
        #pragma unroll
        for (int j = 0; j < 4; ++j)
          acc[i][j] += av[i] * bv[j];
    }
    __syncthreads();
  }
  #pragma unroll
  for (int i = 0; i < 8; ++i) {
    const int m = m0 + ty * 8 + i;
    if (m >= M) continue;
    #pragma unroll
    for (int j = 0; j < 4; ++j) {
      const int n = n0 + tx * 4 + j;
      if (n >= N) continue;
      float v = acc[i][j] + bias[n];
      if (ACT == 1) v = eluf(v);
      if (ACT == 2) {
        if (n < 1024) C[(size_t)m * 1024 + n] = v;
        else          C[(size_t)m * 1024 + (n - 1024) + 1024 * 1024] = softplusf(v) + 0.1f;
      } else {
        C[(size_t)m * ldc + n] = v;
      }
    }
  }
}

extern "C" void kernel_launch(void* const* d_in, const int* in_sizes, int n_in,
                              void* d_out, int out_size, void* d_ws, size_t ws_size,
                              hipStream_t stream)
{
  const float* obs      = (const float*)d_in[0];
  const float* acts     = (const float*)d_in[1];
  const float* noise    = (const float*)d_in[2];
  const float* enc_w    = (const float*)d_in[3];
  const float* enc_b    = (const float*)d_in[4];
  const float* dec_w    = (const float*)d_in[5];
  const float* dec_b    = (const float*)d_in[6];
  const float* p_enc_w  = (const float*)d_in[7];
  const float* p_enc_b  = (const float*)d_in[8];
  const float* gru_wih  = (const float*)d_in[9];
  const float* gru_whh  = (const float*)d_in[10];
  const float* gru_b    = (const float*)d_in[11];
  const float* gru_bn   = (const float*)d_in[12];
  const float* p_dec1_w = (const float*)d_in[13];
  const float* p_dec1_b = (const float*)d_in[14];
  const float* p_dec2_w = (const float*)d_in[15];
  const float* p_dec2_b = (const float*)d_in[16];
  const float* q_enc_w  = (const float*)d_in[17];
  const float* q_enc_b  = (const float*)d_in[18];
  const float* q_dec_w  = (const float*)d_in[19];
  const float* q_dec_b  = (const float*)d_in[20];

  float* out   = (float*)d_out;
  float* stoch = out;                     // [1024,1024]
  float* det   = out + 1048576;           // [1024,2048]
  float* outs  = out + 3145728;           // [1024,1026] — dead during scan; hosts sync data
  float* qmu   = out + 4196352;           // [1024,1024]
  float* qstd  = out + 5244928;           // [1024,1024]
  float* pmu   = out + 6293504;           // [1024,1024] (pstd adjacent)

  // sync structures in the (scan-dead) outs region; final GEMM overwrites it fully.
  unsigned* flags = (unsigned*)outs;      // 4 x 256 x 16 u32 = 64 KB
  float* sv_vals = outs + 16384;          // 1024
  float* xv      = sv_vals + 1024;        // 2048
  float* dvv     = xv + 2048;             // 2048
  float* qvv     = dvv + 2048;            // 2048  (~94 KB total << outs size)

  float* ws       = (float*)d_ws;
  float* pre_act  = ws;                          // 2,097,152 f
  float* pre_e    = ws + 2097152;                // 2,097,152 f
  float* emb      = ws + 4194304;                // 2,097,152 f
  ushort_t* wpack = (ushort_t*)(ws + 6299648);
  ushort_t* wps_lin = wpack;                     //  2,097,152 us (LDS-dest, linear)
  ushort_t* wih_lin = wps_lin + 2097152;         // 12,582,912 us (LDS-dest, linear)
  ushort_t* whh_swz = wih_lin + 12582912;        // 12,582,912 us (reg-dest, swz)
  ushort_t* wqe_swz = whh_swz + 12582912;        //  4,194,304 us (reg-dest, swz)
  ushort_t* wqd_swz = wqe_swz + 4194304;         //  4,194,304 us (reg-dest, swz)

  init_flags<<<dim3(1), dim3(256), 0, stream>>>(flags);

  pack_lin<<<dim3(1024), dim3(256), 0, stream>>>(p_enc_w, (unsigned*)wps_lin, 1088, 10, 1048576);
  pack_lin<<<dim3(1024), dim3(256), 0, stream>>>(gru_wih, (unsigned*)wih_lin, 2048, 11, 6291456);
  pack_swz<<<dim3(1024), dim3(256), 0, stream>>>(gru_whh, (unsigned*)whh_swz, 2048, 11, 6291456);
  pack_swz<<<dim3(1024), dim3(256), 0, stream>>>(q_enc_w, (unsigned*)wqe_swz, 4096, 11, 2097152);
  pack_swz<<<dim3(1024), dim3(256), 0, stream>>>(q_dec_w, (unsigned*)wqd_swz, 2048, 11, 2097152);

  dim3 blk(256);
  gemm_xwT<0><<<dim3(32, 8), blk, 0, stream>>>(
      acts, 64, acts, 64, 64, p_enc_w, 1088, 1024, p_enc_b, pre_act, 2048, 1024, 2048, 64);
  gemm_xwT<1><<<dim3(32, 8), blk, 0, stream>>>(
      obs, 1024, obs, 1024, 1024, enc_w, 1024, 0, enc_b, emb, 2048, 1024, 2048, 1024);
  gemm_xwT<0><<<dim3(32, 8), blk, 0, stream>>>(
      emb, 2048, emb, 2048, 2048, q_enc_w, 4096, 2048, q_enc_b, pre_e, 2048, 1024, 2048, 2048);

  rssm_seq<<<dim3(NWG), dim3(NTHR), 0, stream>>>(
      pre_act, pre_e, flags, sv_vals, xv, dvv, qvv,
      (const unsigned*)wps_lin, (const unsigned*)wih_lin,
      whh_swz, wqe_swz, wqd_swz,
      gru_b, gru_bn, q_dec_b, noise, stoch, det, qmu, qstd);

  gemm_xwT<1><<<dim3(32, 8), blk, 0, stream>>>(
      det, 2048, det, 2048, 2048, p_dec1_w, 2048, 0, p_dec1_b, emb, 2048, 1024, 2048, 2048);
  gemm_xwT<2><<<dim3(32, 8), blk, 0, stream>>>(
      emb, 2048, emb, 2048, 2048, p_dec2_w, 2048, 0, p_dec2_b, pmu, 1024, 1024, 2048, 2048);
  gemm_xwT<0><<<dim3(17, 8), blk, 0, stream>>>(
      stoch, 1024, det, 2048, 1024, dec_w, 3072, 0, dec_b, outs, 1026, 1024, 1026, 3072);
}